// Round 2
// baseline (511.017 us; speedup 1.0000x reference)
//
#include <hip/hip_runtime.h>

typedef unsigned short u16;
typedef unsigned int   u32;
typedef __attribute__((ext_vector_type(8))) short bf16x8;
typedef __attribute__((ext_vector_type(4))) float f32x4;
typedef __attribute__((ext_vector_type(4))) float f4;

#define B_      8
#define HW_     112
#define C_      192
#define NH_     6
#define HD_     32
#define L_      (HW_*HW_)       // 12544
#define M_      (B_*L_)         // 100352
#define MLP_    768
#define QKVN_   576
#define LOG100_ 4.6051702f

__device__ __forceinline__ float bf2f(u16 u){
  union { float f; u32 i; } v; v.i = ((u32)u) << 16; return v.f;
}
__device__ __forceinline__ u16 f2bf(float f){
  union { float f; u32 i; } v; v.f = f;
  u32 r = (v.i + 0x7fffu + ((v.i >> 16) & 1u)) >> 16;
  return (u16)r;
}
__device__ __forceinline__ u32 pk2(float a, float b){
  return (u32)f2bf(a) | ((u32)f2bf(b) << 16);
}
__device__ __forceinline__ void u4_to_f8(uint4 u, float* f){
  f[0]=bf2f((u16)(u.x&0xffffu)); f[1]=bf2f((u16)(u.x>>16));
  f[2]=bf2f((u16)(u.y&0xffffu)); f[3]=bf2f((u16)(u.y>>16));
  f[4]=bf2f((u16)(u.z&0xffffu)); f[5]=bf2f((u16)(u.z>>16));
  f[6]=bf2f((u16)(u.w&0xffffu)); f[7]=bf2f((u16)(u.w>>16));
}

// ---------------- f32 -> bf16 bulk convert -----------------------------------
__global__ __launch_bounds__(256) void f2bf_kernel(
    const float* __restrict__ in, u16* __restrict__ out, int n)
{
  int i = (blockIdx.x*256 + threadIdx.x)*8;
  if (i >= n) return;
  float4 a = *(const float4*)(in + i);
  float4 b = *(const float4*)(in + i + 4);
  uint4 u;
  u.x = pk2(a.x, a.y); u.y = pk2(a.z, a.w);
  u.z = pk2(b.x, b.y); u.w = pk2(b.z, b.w);
  *(uint4*)(void*)(out + i) = u;
}

// ---------------- weight prep: transpose to [N][K] bf16, biases f32 ----------
__global__ __launch_bounds__(256) void prep_weights(
    const float* __restrict__ qw, const float* __restrict__ qb,
    const float* __restrict__ kw, const float* __restrict__ vw,
    const float* __restrict__ vb, const float* __restrict__ pw,
    const float* __restrict__ pb, const float* __restrict__ f1w,
    const float* __restrict__ f1b, const float* __restrict__ f2w,
    const float* __restrict__ f2b,
    u16* __restrict__ wt_qkv, float* __restrict__ b_qkv,
    u16* __restrict__ wt_p,   float* __restrict__ b_p,
    u16* __restrict__ wt_f1,  float* __restrict__ b_f1,
    u16* __restrict__ wt_f2,  float* __restrict__ b_f2)
{
  const int S1 = 110592, S2 = 147456, S3 = 294912, S4 = 442368, TOT = 444096;
  int i = blockIdx.x*256 + threadIdx.x;
  if (i >= TOT) return;
  if (i < S1) {                       // wt_qkv[576][192]
    int n = i/192, k = i%192;
    float v = (n<192) ? qw[k*192+n] : ((n<384) ? kw[k*192+(n-192)] : vw[k*192+(n-384)]);
    wt_qkv[i] = f2bf(v);
  } else if (i < S2) {                // wt_p[192][192]
    int j = i - S1; int n = j/192, k = j%192;
    wt_p[j] = f2bf(pw[k*192+n]);
  } else if (i < S3) {                // wt_f1[768][192]
    int j = i - S2; int n = j/192, k = j%192;
    wt_f1[j] = f2bf(f1w[k*768+n]);
  } else if (i < S4) {                // wt_f2[192][768]
    int j = i - S3; int n = j/768, k = j%768;
    wt_f2[j] = f2bf(f2w[k*192+n]);
  } else {
    int j = i - S4;
    if (j < 576)        b_qkv[j] = (j<192) ? qb[j] : ((j<384) ? 0.f : vb[j-384]);
    else if (j < 768)   b_p[j-576]   = pb[j-576];
    else if (j < 1536)  b_f1[j-768]  = f1b[j-768];
    else                b_f2[j-1536] = f2b[j-1536];
  }
}

// ---------------- relative position bias ------------------------------------
__device__ __forceinline__ float reltab(float x){
  float v = x * (8.f/6.f);
  float r = __log2f(fabsf(v) + 1.f) * (1.f/3.f);
  return (v < 0.f) ? -r : r;
}

__global__ __launch_bounds__(256) void rpb_a_kernel(
    const float* __restrict__ w0, const float* __restrict__ b0,
    const float* __restrict__ w1, float* __restrict__ rpb169)
{
  int i = blockIdx.x*256 + threadIdx.x;
  if (i >= 169*6) return;
  int tt = i/6, hh = i%6;
  float t0 = reltab((float)(tt/13 - 6));
  float t1 = reltab((float)(tt%13 - 6));
  float acc = 0.f;
  for (int j=0;j<512;j++){
    float hid = t0*w0[j] + t1*w0[512+j] + b0[j];
    hid = fmaxf(hid, 0.f);
    acc += hid * w1[j*6+hh];
  }
  rpb169[tt*6+hh] = acc;
}

__global__ __launch_bounds__(256) void rpb_b_kernel(
    const float* __restrict__ rpb169, float* __restrict__ rpbf)
{
  int i = blockIdx.x*256 + threadIdx.x;
  if (i >= 6*2401) return;
  int hh = i/2401, rc = i%2401, r = rc/49, c = rc%49;
  int idx = (r/7 - c/7 + 6)*13 + (r%7 - c%7 + 6);
  float x = rpb169[idx*6+hh];
  rpbf[i] = 16.f / (1.f + __expf(-x));
}

// ---------------- bf16 MFMA GEMM: out[M][NN] = act(A[M][K] @ Wt[NN][K]^T + b) -
template<int K, bool GELU>
__global__ __launch_bounds__(256,2) void gemm_kernel(
    const u16* __restrict__ A, const u16* __restrict__ Wt,
    const float* __restrict__ bias, u16* __restrict__ out, int NN)
{
  __shared__ __align__(16) u16 At[128*32];
  __shared__ __align__(16) u16 Bt[96*32];
  const int tid  = threadIdx.x;
  const int wave = tid >> 6, lane = tid & 63;
  const int m0 = blockIdx.x * 128;
  const int n0 = blockIdx.y * 96;
  const int wr = wave >> 1, wc = wave & 1;   // wave tile 64 x 48
  const int lrow = lane >> 2, lslot = lane & 3;
  f32x4 acc[4][3];
#pragma unroll
  for (int mt=0;mt<4;mt++)
#pragma unroll
    for (int nt=0;nt<3;nt++)
      acc[mt][nt] = (f32x4){0.f,0.f,0.f,0.f};

  for (int k0 = 0; k0 < K; k0 += 32) {
#pragma unroll
    for (int tt=0; tt<4; tt++){
      int c = wave*4 + tt;                 // 14 chunks of 1 KiB
      if (c < 8) {
        int r  = c*16 + lrow;
        int gk = lslot ^ ((r >> 1) & 3);   // pre-swizzled global source (T2-style)
        const u16* src = A + (size_t)(m0 + r)*K + k0 + gk*8;
        __builtin_amdgcn_global_load_lds(
            (const __attribute__((address_space(1))) void*)src,
            (__attribute__((address_space(3))) void*)&At[c*512], 16, 0, 0);
      } else if (c < 14) {
        int r  = (c-8)*16 + lrow;
        int gk = lslot ^ ((r >> 1) & 3);
        const u16* src = Wt + (size_t)(n0 + r)*K + k0 + gk*8;
        __builtin_amdgcn_global_load_lds(
            (const __attribute__((address_space(1))) void*)src,
            (__attribute__((address_space(3))) void*)&Bt[(c-8)*512], 16, 0, 0);
      }
    }
    __syncthreads();
    bf16x8 af[4], bfr[3];
#pragma unroll
    for (int mt=0;mt<4;mt++){
      int r = wr*64 + mt*16 + (lane & 15);
      int slot = (lane >> 4) ^ ((r >> 1) & 3);
      af[mt] = *(const bf16x8*)&At[r*32 + slot*8];
    }
#pragma unroll
    for (int nt=0;nt<3;nt++){
      int r = wc*48 + nt*16 + (lane & 15);
      int slot = (lane >> 4) ^ ((r >> 1) & 3);
      bfr[nt] = *(const bf16x8*)&Bt[r*32 + slot*8];
    }
#pragma unroll
    for (int mt=0;mt<4;mt++)
#pragma unroll
      for (int nt=0;nt<3;nt++)
        acc[mt][nt] = __builtin_amdgcn_mfma_f32_16x16x32_bf16(af[mt], bfr[nt], acc[mt][nt], 0, 0, 0);
    __syncthreads();
  }
  // epilogue: C/D layout col=lane&15, row=(lane>>4)*4+reg  [verified m89/m91]
#pragma unroll
  for (int mt=0;mt<4;mt++){
    int rbase = m0 + wr*64 + mt*16 + (lane >> 4)*4;
#pragma unroll
    for (int nt=0;nt<3;nt++){
      int col = n0 + wc*48 + nt*16 + (lane & 15);
      float bs = bias[col];
#pragma unroll
      for (int r2=0;r2<4;r2++){
        float v = acc[mt][nt][r2] + bs;
        if (GELU) {
          float u = 0.79788456080286536f*(v + 0.044715f*v*v*v);
          v = 0.5f*v*(1.f + tanhf(u));
        }
        out[(size_t)(rbase + r2)*NN + col] = f2bf(v);
      }
    }
  }
}

// ---------------- windowed cosine attention ----------------------------------
// one wave per (window, head); gather rows by shift/window map; scatter back
__global__ __launch_bounds__(64) void attn_kernel(
    const u16* __restrict__ qkv, const float* __restrict__ lsc,
    const float* __restrict__ rpbf, u16* __restrict__ attn_out)
{
  __shared__ __align__(16) float kn[49*36];  // padded rows: 36 floats (9 f4)
  __shared__ __align__(16) float vv[49*36];
  const int id = blockIdx.x;
  const int hh = id % 6;
  const int w  = id / 6;
  const int b  = w >> 8;
  const int wi = w & 255;
  const int wh = wi >> 4, ww = wi & 15;
  const int t  = threadIdx.x;
  const float scale = __expf(fminf(lsc[hh], LOG100_));

  float q[32];
  size_t row = 0;
  if (t < 49) {
    int i  = t / 7, j = t % 7;
    int oi = (wh*7 + i + 3) % 112;           // inverse of roll(-3)
    int oj = (ww*7 + j + 3) % 112;
    row = (size_t)b*L_ + (size_t)oi*112 + oj;
    const u16* base = qkv + row*QKVN_;
    float ss = 0.f;
#pragma unroll
    for (int sc=0; sc<4; sc++){
      uint4 u = *(const uint4*)(const void*)(base + hh*32 + sc*8);
      u4_to_f8(u, &q[sc*8]);
    }
#pragma unroll
    for (int d=0; d<32; d++) ss += q[d]*q[d];
    float rn = 1.f / fmaxf(sqrtf(ss), 1e-6f);
#pragma unroll
    for (int d=0; d<32; d++) q[d] *= rn;
    // K: rotated 16B chunks -> bank-conflict-free LDS writes
    float kf[4][8]; ss = 0.f;
#pragma unroll
    for (int si=0; si<4; si++){
      int sc = (t + si) & 3;
      uint4 u = *(const uint4*)(const void*)(base + 192 + hh*32 + sc*8);
      u4_to_f8(u, kf[si]);
    }
#pragma unroll
    for (int si=0; si<4; si++)
#pragma unroll
      for (int d=0; d<8; d++) ss += kf[si][d]*kf[si][d];
    rn = 1.f / fmaxf(sqrtf(ss), 1e-6f);
#pragma unroll
    for (int si=0; si<4; si++){
      int sc = (t + si) & 3;
      f4* dst = (f4*)&kn[t*36 + sc*8];
      f4 d0 = { kf[si][0]*rn, kf[si][1]*rn, kf[si][2]*rn, kf[si][3]*rn };
      f4 d1 = { kf[si][4]*rn, kf[si][5]*rn, kf[si][6]*rn, kf[si][7]*rn };
      dst[0] = d0; dst[1] = d1;
    }
#pragma unroll
    for (int si=0; si<4; si++){
      int sc = (t + si) & 3;
      uint4 u = *(const uint4*)(const void*)(base + 384 + hh*32 + sc*8);
      float vf[8]; u4_to_f8(u, vf);
      f4* dst = (f4*)&vv[t*36 + sc*8];
      f4 d0 = { vf[0], vf[1], vf[2], vf[3] };
      f4 d1 = { vf[4], vf[5], vf[6], vf[7] };
      dst[0] = d0; dst[1] = d1;
    }
  }
  __syncthreads();
  if (t >= 49) return;

  const f4* kn4 = (const f4*)kn;
  float s[49];
#pragma unroll
  for (int c=0; c<49; c++){
    float a0=0.f,a1=0.f,a2=0.f,a3=0.f;
#pragma unroll
    for (int d4=0; d4<8; d4++){
      f4 kc = kn4[c*9 + d4];   // broadcast read: conflict-free
      a0 += q[d4*4+0]*kc.x;
      a1 += q[d4*4+1]*kc.y;
      a2 += q[d4*4+2]*kc.z;
      a3 += q[d4*4+3]*kc.w;
    }
    s[c] = scale*((a0+a1)+(a2+a3));
  }
  {
    int it = t/7, jt = t%7;
    int idr = ((wh==15) ? (it<4?1:2) : 0)*3 + ((ww==15) ? (jt<4?1:2) : 0);
    const float* rrow = rpbf + hh*2401 + t*49;
#pragma unroll
    for (int c=0; c<49; c++){
      int ic = c/7, jc = c%7;
      int idc = ((wh==15) ? (ic<4?1:2) : 0)*3 + ((ww==15) ? (jc<4?1:2) : 0);
      s[c] += rrow[c] + ((idc != idr) ? -100.f : 0.f);
    }
  }
  float m = -1e30f;
#pragma unroll
  for (int c=0; c<49; c++) m = fmaxf(m, s[c]);
  float sum = 0.f;
#pragma unroll
  for (int c=0; c<49; c++){ s[c] = __expf(s[c]-m); sum += s[c]; }
  float rs = 1.f/sum;

  const f4* vv4 = (const f4*)vv;
  float o[32];
#pragma unroll
  for (int d=0; d<32; d++) o[d] = 0.f;
#pragma unroll
  for (int c=0; c<49; c++){
    float pc = s[c];
#pragma unroll
    for (int d4=0; d4<8; d4++){
      f4 vc = vv4[c*9 + d4];
      o[d4*4+0] += pc*vc.x;
      o[d4*4+1] += pc*vc.y;
      o[d4*4+2] += pc*vc.z;
      o[d4*4+3] += pc*vc.w;
    }
  }
  u16* op = attn_out + row*C_ + hh*32;
#pragma unroll
  for (int d8=0; d8<4; d8++){
    uint4 u;
    u.x = pk2(o[d8*8+0]*rs, o[d8*8+1]*rs);
    u.y = pk2(o[d8*8+2]*rs, o[d8*8+3]*rs);
    u.z = pk2(o[d8*8+4]*rs, o[d8*8+5]*rs);
    u.w = pk2(o[d8*8+6]*rs, o[d8*8+7]*rs);
    *(uint4*)(void*)(op + d8*8) = u;
  }
}

// ------ residual + LayerNorm: out = base + LN(y)*g + b  (dtype-templated) ----
template<bool BASE32, bool OUT32>
__global__ __launch_bounds__(256) void ln_res_kernel(
    const float* __restrict__ base32, const u16* __restrict__ base16,
    const u16* __restrict__ y,
    const float* __restrict__ gg, const float* __restrict__ bb,
    float* __restrict__ out32, u16* __restrict__ out16,
    u16* __restrict__ out16b)   // optional second bf16 copy (may be null)
{
  int row  = blockIdx.x*4 + (threadIdx.x >> 6);
  int lane = threadIdx.x & 63;
  size_t ro = (size_t)row*192;
  float v0 = bf2f(y[ro+lane]), v1 = bf2f(y[ro+lane+64]), v2 = bf2f(y[ro+lane+128]);
  float s  = v0+v1+v2;
  float sq = v0*v0+v1*v1+v2*v2;
#pragma unroll
  for (int m=32; m>=1; m>>=1){ s += __shfl_xor(s,m); sq += __shfl_xor(sq,m); }
  float mean = s*(1.f/192.f);
  float var  = fmaxf(sq*(1.f/192.f) - mean*mean, 0.f);
  float rstd = rsqrtf(var + 1e-5f);
  float g0=gg[lane], g1=gg[lane+64], g2=gg[lane+128];
  float b0=bb[lane], b1=bb[lane+64], b2=bb[lane+128];
  float a0, a1, a2;
  if (BASE32) { a0=base32[ro+lane]; a1=base32[ro+lane+64]; a2=base32[ro+lane+128]; }
  else        { a0=bf2f(base16[ro+lane]); a1=bf2f(base16[ro+lane+64]); a2=bf2f(base16[ro+lane+128]); }
  float r0 = a0 + (v0-mean)*rstd*g0 + b0;
  float r1 = a1 + (v1-mean)*rstd*g1 + b1;
  float r2 = a2 + (v2-mean)*rstd*g2 + b2;
  if (OUT32) {
    out32[ro+lane] = r0; out32[ro+lane+64] = r1; out32[ro+lane+128] = r2;
  } else {
    out16[ro+lane] = f2bf(r0); out16[ro+lane+64] = f2bf(r1); out16[ro+lane+128] = f2bf(r2);
  }
  (void)out16b;
}

// ---------------- launch ------------------------------------------------------
extern "C" void kernel_launch(void* const* d_in, const int* in_sizes, int n_in,
                              void* d_out, int out_size, void* d_ws, size_t ws_size,
                              hipStream_t stream)
{
  (void)in_sizes; (void)n_in; (void)out_size; (void)ws_size;
  const float* x      = (const float*)d_in[0];
  const float* q_w    = (const float*)d_in[1];
  const float* q_b    = (const float*)d_in[2];
  const float* k_w    = (const float*)d_in[3];
  const float* v_w    = (const float*)d_in[4];
  const float* v_b    = (const float*)d_in[5];
  const float* proj_w = (const float*)d_in[6];
  const float* proj_b = (const float*)d_in[7];
  const float* lsc    = (const float*)d_in[8];
  const float* cpb_w0 = (const float*)d_in[9];
  const float* cpb_b0 = (const float*)d_in[10];
  const float* cpb_w1 = (const float*)d_in[11];
  const float* ln1_g  = (const float*)d_in[12];
  const float* ln1_b  = (const float*)d_in[13];
  const float* ln2_g  = (const float*)d_in[14];
  const float* ln2_b  = (const float*)d_in[15];
  const float* fc1_w  = (const float*)d_in[16];
  const float* fc1_b  = (const float*)d_in[17];
  const float* fc2_w  = (const float*)d_in[18];
  const float* fc2_b  = (const float*)d_in[19];

  char* ws = (char*)d_ws;
  size_t o = 0;
  // region A: 154.1 MB — qkvb (115.6 MB) then mid (154.1 MB)
  u16* qkvb = (u16*)(ws + o);
  u16* mid  = qkvb;              o += 154140672;
  // region B: 38.5 MB — x_bf, then attn_o, then h1b
  u16* x_bf   = (u16*)(ws + o);
  u16* attn_o = x_bf;
  u16* h1b    = x_bf;            o += 38535168;
  // region C: 38.5 MB — proj_o, then m2
  u16* proj_o = (u16*)(ws + o);
  u16* m2     = proj_o;          o += 38535168;
  u16* wt_qkv = (u16*)(ws + o);  o += 221184;
  float* b_qkv= (float*)(ws + o);o += 2304;
  u16* wt_p   = (u16*)(ws + o);  o += 73728;
  float* b_p  = (float*)(ws + o);o += 768;
  u16* wt_f1  = (u16*)(ws + o);  o += 294912;
  float* b_f1 = (float*)(ws + o);o += 3072;
  u16* wt_f2  = (u16*)(ws + o);  o += 294912;
  float* b_f2 = (float*)(ws + o);o += 768;
  float* rpb169 = (float*)(ws + o); o += 4096;
  float* rpbf   = (float*)(ws + o); o += 57856;

  prep_weights<<<1735, 256, 0, stream>>>(q_w, q_b, k_w, v_w, v_b, proj_w, proj_b,
      fc1_w, fc1_b, fc2_w, fc2_b, wt_qkv, b_qkv, wt_p, b_p, wt_f1, b_f1, wt_f2, b_f2);
  rpb_a_kernel<<<4, 256, 0, stream>>>(cpb_w0, cpb_b0, cpb_w1, rpb169);
  rpb_b_kernel<<<57, 256, 0, stream>>>(rpb169, rpbf);
  f2bf_kernel<<<9408, 256, 0, stream>>>(x, x_bf, M_*C_);

  gemm_kernel<192,false><<<dim3(784,6), 256, 0, stream>>>(x_bf, wt_qkv, b_qkv, qkvb, 576);
  attn_kernel<<<12288, 64, 0, stream>>>(qkvb, lsc, rpbf, attn_o);
  gemm_kernel<192,false><<<dim3(784,2), 256, 0, stream>>>(attn_o, wt_p, b_p, proj_o, 192);
  // h1b = x + LN(proj_o)   (bf16; x read as f32)
  ln_res_kernel<true,false><<<25088, 256, 0, stream>>>(x, nullptr, proj_o,
      ln1_g, ln1_b, nullptr, h1b, nullptr);
  gemm_kernel<192,true><<<dim3(784,8), 256, 0, stream>>>(h1b, wt_f1, b_f1, mid, 768);
  gemm_kernel<768,false><<<dim3(784,2), 256, 0, stream>>>(mid, wt_f2, b_f2, m2, 192);
  // out = h1b + LN(m2)   (f32 out)
  ln_res_kernel<false,true><<<25088, 256, 0, stream>>>(nullptr, h1b, m2,
      ln2_g, ln2_b, (float*)d_out, nullptr, nullptr);
}

// Round 3
// 419.529 us; speedup vs baseline: 1.2181x; 1.2181x over previous
//
#include <hip/hip_runtime.h>

typedef unsigned short u16;
typedef unsigned int   u32;
typedef __attribute__((ext_vector_type(8))) short bf16x8;
typedef __attribute__((ext_vector_type(4))) float f32x4;

#define B_      8
#define HW_     112
#define C_      192
#define NH_     6
#define HD_     32
#define L_      (HW_*HW_)       // 12544
#define M_      (B_*L_)         // 100352
#define MLP_    768
#define QKVN_   576
#define LOG100_ 4.6051702f
#define LOG2E_  1.44269504f

__device__ __forceinline__ float bf2f(u16 u){
  union { float f; u32 i; } v; v.i = ((u32)u) << 16; return v.f;
}
__device__ __forceinline__ u16 f2bf(float f){
  union { float f; u32 i; } v; v.f = f;
  u32 r = (v.i + 0x7fffu + ((v.i >> 16) & 1u)) >> 16;
  return (u16)r;
}
__device__ __forceinline__ u32 pk2(float a, float b){
  return (u32)f2bf(a) | ((u32)f2bf(b) << 16);
}
__device__ __forceinline__ void u4_to_f8(uint4 u, float* f){
  f[0]=bf2f((u16)(u.x&0xffffu)); f[1]=bf2f((u16)(u.x>>16));
  f[2]=bf2f((u16)(u.y&0xffffu)); f[3]=bf2f((u16)(u.y>>16));
  f[4]=bf2f((u16)(u.z&0xffffu)); f[5]=bf2f((u16)(u.z>>16));
  f[6]=bf2f((u16)(u.w&0xffffu)); f[7]=bf2f((u16)(u.w>>16));
}

// local window index t (0..48) -> token row (elements) with reverse cyclic shift
__device__ __forceinline__ int rowelem(int b, int wh, int ww, int t){
  int i = t/7, j = t - i*7;
  int oi = wh*7 + i + 3; if (oi >= 112) oi -= 112;
  int oj = ww*7 + j + 3; if (oj >= 112) oj -= 112;
  return b*L_ + oi*112 + oj;
}

// ---------------- f32 -> bf16 bulk convert -----------------------------------
__global__ __launch_bounds__(256) void f2bf_kernel(
    const float* __restrict__ in, u16* __restrict__ out, int n)
{
  int i = (blockIdx.x*256 + threadIdx.x)*8;
  if (i >= n) return;
  float4 a = *(const float4*)(in + i);
  float4 b = *(const float4*)(in + i + 4);
  uint4 u;
  u.x = pk2(a.x, a.y); u.y = pk2(a.z, a.w);
  u.z = pk2(b.x, b.y); u.w = pk2(b.z, b.w);
  *(uint4*)(void*)(out + i) = u;
}

// ---------------- weight prep: transpose to [N][K] bf16, biases f32 ----------
__global__ __launch_bounds__(256) void prep_weights(
    const float* __restrict__ qw, const float* __restrict__ qb,
    const float* __restrict__ kw, const float* __restrict__ vw,
    const float* __restrict__ vb, const float* __restrict__ pw,
    const float* __restrict__ pb, const float* __restrict__ f1w,
    const float* __restrict__ f1b, const float* __restrict__ f2w,
    const float* __restrict__ f2b,
    u16* __restrict__ wt_qkv, float* __restrict__ b_qkv,
    u16* __restrict__ wt_p,   float* __restrict__ b_p,
    u16* __restrict__ wt_f1,  float* __restrict__ b_f1,
    u16* __restrict__ wt_f2,  float* __restrict__ b_f2)
{
  const int S1 = 110592, S2 = 147456, S3 = 294912, S4 = 442368, TOT = 444096;
  int i = blockIdx.x*256 + threadIdx.x;
  if (i >= TOT) return;
  if (i < S1) {                       // wt_qkv[576][192]
    int n = i/192, k = i%192;
    float v = (n<192) ? qw[k*192+n] : ((n<384) ? kw[k*192+(n-192)] : vw[k*192+(n-384)]);
    wt_qkv[i] = f2bf(v);
  } else if (i < S2) {                // wt_p[192][192]
    int j = i - S1; int n = j/192, k = j%192;
    wt_p[j] = f2bf(pw[k*192+n]);
  } else if (i < S3) {                // wt_f1[768][192]
    int j = i - S2; int n = j/192, k = j%192;
    wt_f1[j] = f2bf(f1w[k*768+n]);
  } else if (i < S4) {                // wt_f2[192][768]
    int j = i - S3; int n = j/768, k = j%768;
    wt_f2[j] = f2bf(f2w[k*192+n]);
  } else {
    int j = i - S4;
    if (j < 576)        b_qkv[j] = (j<192) ? qb[j] : ((j<384) ? 0.f : vb[j-384]);
    else if (j < 768)   b_p[j-576]   = pb[j-576];
    else if (j < 1536)  b_f1[j-768]  = f1b[j-768];
    else                b_f2[j-1536] = f2b[j-1536];
  }
}

// ---------------- relative position bias ------------------------------------
__device__ __forceinline__ float reltab(float x){
  float v = x * (8.f/6.f);
  float r = __log2f(fabsf(v) + 1.f) * (1.f/3.f);
  return (v < 0.f) ? -r : r;
}

__global__ __launch_bounds__(64) void rpb_a_kernel(
    const float* __restrict__ w0, const float* __restrict__ b0,
    const float* __restrict__ w1, float* __restrict__ rpb169)
{
  int tt = blockIdx.x, lane = threadIdx.x;
  float t0 = reltab((float)(tt/13 - 6));
  float t1 = reltab((float)(tt%13 - 6));
  float acc[6] = {0.f,0.f,0.f,0.f,0.f,0.f};
  for (int j = lane; j < 512; j += 64){
    float hid = fmaxf(t0*w0[j] + t1*w0[512+j] + b0[j], 0.f);
#pragma unroll
    for (int h=0; h<6; h++) acc[h] += hid * w1[j*6+h];
  }
#pragma unroll
  for (int h=0; h<6; h++){
#pragma unroll
    for (int m=32; m>=1; m>>=1) acc[h] += __shfl_xor(acc[h], m);
  }
  if (lane == 0){
#pragma unroll
    for (int h=0; h<6; h++) rpb169[tt*6+h] = acc[h];
  }
}

// biasT[type][head][key(64)][q(64)] = (16*sigmoid(rpb) + mask) * log2(e)
// key>=49 -> -60000 (kills padded keys); q>=49 rows unused.
__global__ __launch_bounds__(256) void rpb_b_kernel(
    const float* __restrict__ rpb169, float* __restrict__ biasT)
{
  int i = blockIdx.x*256 + threadIdx.x;   // 4*6*64*64 = 98304
  if (i >= 98304) return;
  int q = i & 63, key = (i >> 6) & 63;
  int rest = i >> 12;                      // 0..23
  int hh = rest % 6, type = rest / 6;
  float val;
  if (key >= 49) val = -60000.f;
  else if (q >= 49) val = 0.f;
  else {
    int qi = q/7, qj = q%7, ki = key/7, kj = key%7;
    int idx = (qi - ki + 6)*13 + (qj - kj + 6);
    float x = rpb169[idx*6 + hh];
    float sig = 16.f / (1.f + __expf(-x));
    int th = type >> 1, tw = type & 1;
    int rq = (th ? (qi<4?1:2) : 0)*3 + (tw ? (qj<4?1:2) : 0);
    int rk = (th ? (ki<4?1:2) : 0)*3 + (tw ? (kj<4?1:2) : 0);
    float msk = (rq != rk) ? -100.f : 0.f;
    val = (sig + msk) * LOG2E_;
  }
  biasT[i] = val;
}

// ---------------- bf16 MFMA GEMM: out[M][NN] = act(A[M][K] @ Wt[NN][K]^T + b) -
template<int K, bool GELU>
__global__ __launch_bounds__(256,2) void gemm_kernel(
    const u16* __restrict__ A, const u16* __restrict__ Wt,
    const float* __restrict__ bias, u16* __restrict__ out, int NN)
{
  __shared__ __align__(16) u16 At[128*32];
  __shared__ __align__(16) u16 Bt[96*32];
  const int tid  = threadIdx.x;
  const int wave = tid >> 6, lane = tid & 63;
  const int m0 = blockIdx.x * 128;
  const int n0 = blockIdx.y * 96;
  const int wr = wave >> 1, wc = wave & 1;   // wave tile 64 x 48
  const int lrow = lane >> 2, lslot = lane & 3;
  f32x4 acc[4][3];
#pragma unroll
  for (int mt=0;mt<4;mt++)
#pragma unroll
    for (int nt=0;nt<3;nt++)
      acc[mt][nt] = (f32x4){0.f,0.f,0.f,0.f};

  for (int k0 = 0; k0 < K; k0 += 32) {
#pragma unroll
    for (int tt=0; tt<4; tt++){
      int c = wave*4 + tt;                 // 14 chunks of 1 KiB
      if (c < 8) {
        int r  = c*16 + lrow;
        int gk = lslot ^ ((r >> 1) & 3);   // pre-swizzled global source
        const u16* src = A + (size_t)(m0 + r)*K + k0 + gk*8;
        __builtin_amdgcn_global_load_lds(
            (const __attribute__((address_space(1))) void*)src,
            (__attribute__((address_space(3))) void*)&At[c*512], 16, 0, 0);
      } else if (c < 14) {
        int r  = (c-8)*16 + lrow;
        int gk = lslot ^ ((r >> 1) & 3);
        const u16* src = Wt + (size_t)(n0 + r)*K + k0 + gk*8;
        __builtin_amdgcn_global_load_lds(
            (const __attribute__((address_space(1))) void*)src,
            (__attribute__((address_space(3))) void*)&Bt[(c-8)*512], 16, 0, 0);
      }
    }
    __syncthreads();
    bf16x8 af[4], bfr[3];
#pragma unroll
    for (int mt=0;mt<4;mt++){
      int r = wr*64 + mt*16 + (lane & 15);
      int slot = (lane >> 4) ^ ((r >> 1) & 3);
      af[mt] = *(const bf16x8*)&At[r*32 + slot*8];
    }
#pragma unroll
    for (int nt=0;nt<3;nt++){
      int r = wc*48 + nt*16 + (lane & 15);
      int slot = (lane >> 4) ^ ((r >> 1) & 3);
      bfr[nt] = *(const bf16x8*)&Bt[r*32 + slot*8];
    }
#pragma unroll
    for (int mt=0;mt<4;mt++)
#pragma unroll
      for (int nt=0;nt<3;nt++)
        acc[mt][nt] = __builtin_amdgcn_mfma_f32_16x16x32_bf16(af[mt], bfr[nt], acc[mt][nt], 0, 0, 0);
    __syncthreads();
  }
#pragma unroll
  for (int mt=0;mt<4;mt++){
    int rbase = m0 + wr*64 + mt*16 + (lane >> 4)*4;
#pragma unroll
    for (int nt=0;nt<3;nt++){
      int col = n0 + wc*48 + nt*16 + (lane & 15);
      float bs = bias[col];
#pragma unroll
      for (int r2=0;r2<4;r2++){
        float v = acc[mt][nt][r2] + bs;
        if (GELU) {
          float u = 0.79788456080286536f*(v + 0.044715f*v*v*v);
          v = 0.5f*v*(1.f + tanhf(u));
        }
        out[(size_t)(rbase + r2)*NN + col] = f2bf(v);
      }
    }
  }
}

// ---------------- windowed cosine attention, MFMA ----------------------------
// one wave per (window, head): QK^T and PV on matrix cores; P through
// XOR-swizzled LDS; bias+mask+rpb pre-baked (log2 domain) in biasT.
__global__ __launch_bounds__(64) void attn_kernel(
    const u16* __restrict__ qkv, const float* __restrict__ lsc,
    const float* __restrict__ biasT, u16* __restrict__ attn_out)
{
  __shared__ __align__(16) u16 pbuf[4096];   // P[64 q][64 key] bf16, swizzled
  const int id = blockIdx.x;
  const int hh = id % 6;
  const int w  = id / 6;
  const int b  = w >> 8;
  const int wh = (w >> 4) & 15, ww = w & 15;
  const int lane = threadIdx.x;
  const int lg = lane >> 4, lr = lane & 15;
  const int type = ((wh==15)?2:0) + ((ww==15)?1:0);
  const float qscale = __expf(fminf(lsc[hh], LOG100_)) * LOG2E_;

  union BU { bf16x8 v; u32 u[4]; };

  // ---- Q (scale folded) and K fragments, row-normalized -----------------
  bf16x8 qf[4], kf[4];
#pragma unroll
  for (int mt=0; mt<4; mt++){
    int t = mt*16 + lr; if (t > 48) t = 48;
    int off = rowelem(b, wh, ww, t)*QKVN_ + hh*32 + lg*8;
    uint4 u = *(const uint4*)(qkv + off);
    float f[8]; u4_to_f8(u, f);
    float ss = 0.f;
#pragma unroll
    for (int d=0; d<8; d++) ss += f[d]*f[d];
    ss += __shfl_xor(ss, 16); ss += __shfl_xor(ss, 32);
    float rn = qscale / fmaxf(sqrtf(ss), 1e-6f);
    BU bu;
#pragma unroll
    for (int p=0; p<4; p++) bu.u[p] = pk2(f[2*p]*rn, f[2*p+1]*rn);
    qf[mt] = bu.v;
  }
#pragma unroll
  for (int nt=0; nt<4; nt++){
    int t = nt*16 + lr; if (t > 48) t = 48;
    int off = rowelem(b, wh, ww, t)*QKVN_ + 192 + hh*32 + lg*8;
    uint4 u = *(const uint4*)(qkv + off);
    float f[8]; u4_to_f8(u, f);
    float ss = 0.f;
#pragma unroll
    for (int d=0; d<8; d++) ss += f[d]*f[d];
    ss += __shfl_xor(ss, 16); ss += __shfl_xor(ss, 32);
    float rn = 1.f / fmaxf(sqrtf(ss), 1e-6f);
    BU bu;
#pragma unroll
    for (int p=0; p<4; p++) bu.u[p] = pk2(f[2*p]*rn, f[2*p+1]*rn);
    kf[nt] = bu.v;
  }

  // ---- S = Q^ K^T (log2 domain) + bias table -----------------------------
  f32x4 s[4][4];
#pragma unroll
  for (int mt=0;mt<4;mt++)
#pragma unroll
    for (int nt=0;nt<4;nt++)
      s[mt][nt] = __builtin_amdgcn_mfma_f32_16x16x32_bf16(qf[mt], kf[nt],
                    (f32x4){0.f,0.f,0.f,0.f}, 0, 0, 0);

  const float* bt = biasT + (size_t)(type*6 + hh)*4096;
#pragma unroll
  for (int nt=0;nt<4;nt++){
    int key = nt*16 + lr;
#pragma unroll
    for (int mt=0;mt<4;mt++){
      f32x4 bv = *(const f32x4*)(bt + key*64 + mt*16 + lg*4);
      s[mt][nt] += bv;
    }
  }

  // ---- row softmax (16-lane groups hold a row across nt) ----------------
  float rsum[4][4];
#pragma unroll
  for (int mt=0;mt<4;mt++){
#pragma unroll
    for (int r2=0;r2<4;r2++){
      float m = fmaxf(fmaxf(s[mt][0][r2], s[mt][1][r2]),
                      fmaxf(s[mt][2][r2], s[mt][3][r2]));
      m = fmaxf(m, __shfl_xor(m, 1));
      m = fmaxf(m, __shfl_xor(m, 2));
      m = fmaxf(m, __shfl_xor(m, 4));
      m = fmaxf(m, __shfl_xor(m, 8));
      float e0 = exp2f(s[mt][0][r2]-m), e1 = exp2f(s[mt][1][r2]-m),
            e2 = exp2f(s[mt][2][r2]-m), e3 = exp2f(s[mt][3][r2]-m);
      s[mt][0][r2]=e0; s[mt][1][r2]=e1; s[mt][2][r2]=e2; s[mt][3][r2]=e3;
      float sum = (e0+e1)+(e2+e3);
      sum += __shfl_xor(sum, 1);
      sum += __shfl_xor(sum, 2);
      sum += __shfl_xor(sum, 4);
      sum += __shfl_xor(sum, 8);
      rsum[mt][r2] = 1.f/sum;
    }
  }

  // ---- P -> LDS (bf16, XOR-swizzled rows) --------------------------------
#pragma unroll
  for (int mt=0;mt<4;mt++)
#pragma unroll
    for (int r2=0;r2<4;r2++){
      int q = mt*16 + lg*4 + r2;
#pragma unroll
      for (int nt=0;nt<4;nt++){
        int key = nt*16 + lr;
        int addr = (q*128 + key*2) ^ ((q&7)<<4);
        *(u16*)((char*)pbuf + addr) = f2bf(s[mt][nt][r2]);
      }
    }
  __syncthreads();

  // ---- O = P V ------------------------------------------------------------
  f32x4 o[4][2];
#pragma unroll
  for (int mt=0;mt<4;mt++)
#pragma unroll
    for (int dt=0;dt<2;dt++)
      o[mt][dt] = (f32x4){0.f,0.f,0.f,0.f};

#pragma unroll
  for (int kt=0; kt<2; kt++){
    bf16x8 pf[4];
#pragma unroll
    for (int mt=0;mt<4;mt++){
      int q = mt*16 + lr;
      int addr = (q*128 + kt*64 + lg*16) ^ ((q&7)<<4);
      pf[mt] = *(const bf16x8*)((char*)pbuf + addr);
    }
    int voff[8];
#pragma unroll
    for (int j=0;j<8;j++){
      int key = kt*32 + lg*8 + j; if (key > 48) key = 48;
      voff[j] = rowelem(b, wh, ww, key)*QKVN_ + 384 + hh*32 + lr;
    }
#pragma unroll
    for (int dt=0; dt<2; dt++){
      BU bu;
#pragma unroll
      for (int p=0;p<4;p++){
        u16 lo = qkv[voff[2*p]   + dt*16];
        u16 hi = qkv[voff[2*p+1] + dt*16];
        bu.u[p] = (u32)lo | ((u32)hi << 16);
      }
#pragma unroll
      for (int mt=0;mt<4;mt++)
        o[mt][dt] = __builtin_amdgcn_mfma_f32_16x16x32_bf16(pf[mt], bu.v, o[mt][dt], 0, 0, 0);
    }
  }

  // ---- epilogue -----------------------------------------------------------
#pragma unroll
  for (int mt=0;mt<4;mt++)
#pragma unroll
    for (int r2=0;r2<4;r2++){
      int q = mt*16 + lg*4 + r2;
      if (q < 49){
        int off = rowelem(b, wh, ww, q)*C_ + hh*32 + lr;
        float rs = rsum[mt][r2];
        attn_out[off]      = f2bf(o[mt][0][r2]*rs);
        attn_out[off + 16] = f2bf(o[mt][1][r2]*rs);
      }
    }
}

// ------ residual + LayerNorm: out = base + LN(y)*g + b  (dtype-templated) ----
template<bool BASE32, bool OUT32>
__global__ __launch_bounds__(256) void ln_res_kernel(
    const float* __restrict__ base32, const u16* __restrict__ base16,
    const u16* __restrict__ y,
    const float* __restrict__ gg, const float* __restrict__ bb,
    float* __restrict__ out32, u16* __restrict__ out16)
{
  int row  = blockIdx.x*4 + (threadIdx.x >> 6);
  int lane = threadIdx.x & 63;
  size_t ro = (size_t)row*192;
  float v0 = bf2f(y[ro+lane]), v1 = bf2f(y[ro+lane+64]), v2 = bf2f(y[ro+lane+128]);
  float s  = v0+v1+v2;
  float sq = v0*v0+v1*v1+v2*v2;
#pragma unroll
  for (int m=32; m>=1; m>>=1){ s += __shfl_xor(s,m); sq += __shfl_xor(sq,m); }
  float mean = s*(1.f/192.f);
  float var  = fmaxf(sq*(1.f/192.f) - mean*mean, 0.f);
  float rstd = rsqrtf(var + 1e-5f);
  float g0=gg[lane], g1=gg[lane+64], g2=gg[lane+128];
  float b0=bb[lane], b1=bb[lane+64], b2=bb[lane+128];
  float a0, a1, a2;
  if (BASE32) { a0=base32[ro+lane]; a1=base32[ro+lane+64]; a2=base32[ro+lane+128]; }
  else        { a0=bf2f(base16[ro+lane]); a1=bf2f(base16[ro+lane+64]); a2=bf2f(base16[ro+lane+128]); }
  float r0 = a0 + (v0-mean)*rstd*g0 + b0;
  float r1 = a1 + (v1-mean)*rstd*g1 + b1;
  float r2 = a2 + (v2-mean)*rstd*g2 + b2;
  if (OUT32) {
    out32[ro+lane] = r0; out32[ro+lane+64] = r1; out32[ro+lane+128] = r2;
  } else {
    out16[ro+lane] = f2bf(r0); out16[ro+lane+64] = f2bf(r1); out16[ro+lane+128] = f2bf(r2);
  }
}

// ---------------- launch ------------------------------------------------------
extern "C" void kernel_launch(void* const* d_in, const int* in_sizes, int n_in,
                              void* d_out, int out_size, void* d_ws, size_t ws_size,
                              hipStream_t stream)
{
  (void)in_sizes; (void)n_in; (void)out_size; (void)ws_size;
  const float* x      = (const float*)d_in[0];
  const float* q_w    = (const float*)d_in[1];
  const float* q_b    = (const float*)d_in[2];
  const float* k_w    = (const float*)d_in[3];
  const float* v_w    = (const float*)d_in[4];
  const float* v_b    = (const float*)d_in[5];
  const float* proj_w = (const float*)d_in[6];
  const float* proj_b = (const float*)d_in[7];
  const float* lsc    = (const float*)d_in[8];
  const float* cpb_w0 = (const float*)d_in[9];
  const float* cpb_b0 = (const float*)d_in[10];
  const float* cpb_w1 = (const float*)d_in[11];
  const float* ln1_g  = (const float*)d_in[12];
  const float* ln1_b  = (const float*)d_in[13];
  const float* ln2_g  = (const float*)d_in[14];
  const float* ln2_b  = (const float*)d_in[15];
  const float* fc1_w  = (const float*)d_in[16];
  const float* fc1_b  = (const float*)d_in[17];
  const float* fc2_w  = (const float*)d_in[18];
  const float* fc2_b  = (const float*)d_in[19];

  char* ws = (char*)d_ws;
  size_t o = 0;
  // region A: 154.1 MB — qkvb (115.6 MB) then mid (154.1 MB)
  u16* qkvb = (u16*)(ws + o);
  u16* mid  = qkvb;              o += 154140672;
  // region B: 38.5 MB — x_bf, then attn_o, then h1b
  u16* x_bf   = (u16*)(ws + o);
  u16* attn_o = x_bf;
  u16* h1b    = x_bf;            o += 38535168;
  // region C: 38.5 MB — proj_o, then m2
  u16* proj_o = (u16*)(ws + o);
  u16* m2     = proj_o;          o += 38535168;
  u16* wt_qkv = (u16*)(ws + o);  o += 221184;
  float* b_qkv= (float*)(ws + o);o += 2304;
  u16* wt_p   = (u16*)(ws + o);  o += 73728;
  float* b_p  = (float*)(ws + o);o += 768;
  u16* wt_f1  = (u16*)(ws + o);  o += 294912;
  float* b_f1 = (float*)(ws + o);o += 3072;
  u16* wt_f2  = (u16*)(ws + o);  o += 294912;
  float* b_f2 = (float*)(ws + o);o += 768;
  float* rpb169 = (float*)(ws + o); o += 4096;
  float* biasT  = (float*)(ws + o); o += 393216;

  prep_weights<<<1735, 256, 0, stream>>>(q_w, q_b, k_w, v_w, v_b, proj_w, proj_b,
      fc1_w, fc1_b, fc2_w, fc2_b, wt_qkv, b_qkv, wt_p, b_p, wt_f1, b_f1, wt_f2, b_f2);
  rpb_a_kernel<<<169, 64, 0, stream>>>(cpb_w0, cpb_b0, cpb_w1, rpb169);
  rpb_b_kernel<<<384, 256, 0, stream>>>(rpb169, biasT);
  f2bf_kernel<<<9408, 256, 0, stream>>>(x, x_bf, M_*C_);

  gemm_kernel<192,false><<<dim3(784,6), 256, 0, stream>>>(x_bf, wt_qkv, b_qkv, qkvb, 576);
  attn_kernel<<<12288, 64, 0, stream>>>(qkvb, lsc, biasT, attn_o);
  gemm_kernel<192,false><<<dim3(784,2), 256, 0, stream>>>(attn_o, wt_p, b_p, proj_o, 192);
  ln_res_kernel<true,false><<<25088, 256, 0, stream>>>(x, nullptr, proj_o,
      ln1_g, ln1_b, nullptr, h1b);
  gemm_kernel<192,true><<<dim3(784,8), 256, 0, stream>>>(h1b, wt_f1, b_f1, mid, 768);
  gemm_kernel<768,false><<<dim3(784,2), 256, 0, stream>>>(mid, wt_f2, b_f2, m2, 192);
  ln_res_kernel<false,true><<<25088, 256, 0, stream>>>(nullptr, h1b, m2,
      ln2_g, ln2_b, (float*)d_out, nullptr);
}

// Round 4
// 382.914 us; speedup vs baseline: 1.3345x; 1.0956x over previous
//
#include <hip/hip_runtime.h>

typedef unsigned short u16;
typedef unsigned int   u32;
typedef __attribute__((ext_vector_type(8))) short bf16x8;
typedef __attribute__((ext_vector_type(4))) float f32x4;

#define B_      8
#define HW_     112
#define C_      192
#define NH_     6
#define HD_     32
#define L_      (HW_*HW_)       // 12544
#define M_      (B_*L_)         // 100352
#define MLP_    768
#define QKVN_   576
#define LOG100_ 4.6051702f
#define LOG2E_  1.44269504f

__device__ __forceinline__ float bf2f(u16 u){
  union { float f; u32 i; } v; v.i = ((u32)u) << 16; return v.f;
}
__device__ __forceinline__ u16 f2bf(float f){
  union { float f; u32 i; } v; v.f = f;
  u32 r = (v.i + 0x7fffu + ((v.i >> 16) & 1u)) >> 16;
  return (u16)r;
}
__device__ __forceinline__ u32 pk2(float a, float b){
  return (u32)f2bf(a) | ((u32)f2bf(b) << 16);
}
__device__ __forceinline__ void u4_to_f8(uint4 u, float* f){
  f[0]=bf2f((u16)(u.x&0xffffu)); f[1]=bf2f((u16)(u.x>>16));
  f[2]=bf2f((u16)(u.y&0xffffu)); f[3]=bf2f((u16)(u.y>>16));
  f[4]=bf2f((u16)(u.z&0xffffu)); f[5]=bf2f((u16)(u.z>>16));
  f[6]=bf2f((u16)(u.w&0xffffu)); f[7]=bf2f((u16)(u.w>>16));
}

// local window index t (0..48) -> token row (elements) with reverse cyclic shift
__device__ __forceinline__ int rowelem(int b, int wh, int ww, int t){
  int i = t/7, j = t - i*7;
  int oi = wh*7 + i + 3; if (oi >= 112) oi -= 112;
  int oj = ww*7 + j + 3; if (oj >= 112) oj -= 112;
  return b*L_ + oi*112 + oj;
}

// ---------------- f32 -> bf16 bulk convert -----------------------------------
__global__ __launch_bounds__(256) void f2bf_kernel(
    const float* __restrict__ in, u16* __restrict__ out, int n)
{
  int i = (blockIdx.x*256 + threadIdx.x)*8;
  if (i >= n) return;
  float4 a = *(const float4*)(in + i);
  float4 b = *(const float4*)(in + i + 4);
  uint4 u;
  u.x = pk2(a.x, a.y); u.y = pk2(a.z, a.w);
  u.z = pk2(b.x, b.y); u.w = pk2(b.z, b.w);
  *(uint4*)(void*)(out + i) = u;
}

// ---------------- weight prep: transpose to [N][K] bf16, biases f32 ----------
__global__ __launch_bounds__(256) void prep_weights(
    const float* __restrict__ qw, const float* __restrict__ qb,
    const float* __restrict__ kw, const float* __restrict__ vw,
    const float* __restrict__ vb, const float* __restrict__ pw,
    const float* __restrict__ pb, const float* __restrict__ f1w,
    const float* __restrict__ f1b, const float* __restrict__ f2w,
    const float* __restrict__ f2b,
    u16* __restrict__ wt_qkv, float* __restrict__ b_qkv,
    u16* __restrict__ wt_p,   float* __restrict__ b_p,
    u16* __restrict__ wt_f1,  float* __restrict__ b_f1,
    u16* __restrict__ wt_f2,  float* __restrict__ b_f2)
{
  const int S1 = 110592, S2 = 147456, S3 = 294912, S4 = 442368, TOT = 444096;
  int i = blockIdx.x*256 + threadIdx.x;
  if (i >= TOT) return;
  if (i < S1) {                       // wt_qkv[576][192]
    int n = i/192, k = i%192;
    float v = (n<192) ? qw[k*192+n] : ((n<384) ? kw[k*192+(n-192)] : vw[k*192+(n-384)]);
    wt_qkv[i] = f2bf(v);
  } else if (i < S2) {                // wt_p[192][192]
    int j = i - S1; int n = j/192, k = j%192;
    wt_p[j] = f2bf(pw[k*192+n]);
  } else if (i < S3) {                // wt_f1[768][192]
    int j = i - S2; int n = j/192, k = j%192;
    wt_f1[j] = f2bf(f1w[k*768+n]);
  } else if (i < S4) {                // wt_f2[192][768]
    int j = i - S3; int n = j/768, k = j%768;
    wt_f2[j] = f2bf(f2w[k*192+n]);
  } else {
    int j = i - S4;
    if (j < 576)        b_qkv[j] = (j<192) ? qb[j] : ((j<384) ? 0.f : vb[j-384]);
    else if (j < 768)   b_p[j-576]   = pb[j-576];
    else if (j < 1536)  b_f1[j-768]  = f1b[j-768];
    else                b_f2[j-1536] = f2b[j-1536];
  }
}

// ---------------- relative position bias ------------------------------------
__device__ __forceinline__ float reltab(float x){
  float v = x * (8.f/6.f);
  float r = __log2f(fabsf(v) + 1.f) * (1.f/3.f);
  return (v < 0.f) ? -r : r;
}

__global__ __launch_bounds__(64) void rpb_a_kernel(
    const float* __restrict__ w0, const float* __restrict__ b0,
    const float* __restrict__ w1, float* __restrict__ rpb169)
{
  int tt = blockIdx.x, lane = threadIdx.x;
  float t0 = reltab((float)(tt/13 - 6));
  float t1 = reltab((float)(tt%13 - 6));
  float acc[6] = {0.f,0.f,0.f,0.f,0.f,0.f};
  for (int j = lane; j < 512; j += 64){
    float hid = fmaxf(t0*w0[j] + t1*w0[512+j] + b0[j], 0.f);
#pragma unroll
    for (int h=0; h<6; h++) acc[h] += hid * w1[j*6+h];
  }
#pragma unroll
  for (int h=0; h<6; h++){
#pragma unroll
    for (int m=32; m>=1; m>>=1) acc[h] += __shfl_xor(acc[h], m);
  }
  if (lane == 0){
#pragma unroll
    for (int h=0; h<6; h++) rpb169[tt*6+h] = acc[h];
  }
}

// biasT[type][head][key(64)][q(64)] = (16*sigmoid(rpb) + mask) * log2(e)
__global__ __launch_bounds__(256) void rpb_b_kernel(
    const float* __restrict__ rpb169, float* __restrict__ biasT)
{
  int i = blockIdx.x*256 + threadIdx.x;   // 4*6*64*64 = 98304
  if (i >= 98304) return;
  int q = i & 63, key = (i >> 6) & 63;
  int rest = i >> 12;                      // 0..23
  int hh = rest % 6, type = rest / 6;
  float val;
  if (key >= 49) val = -60000.f;
  else if (q >= 49) val = 0.f;
  else {
    int qi = q/7, qj = q%7, ki = key/7, kj = key%7;
    int idx = (qi - ki + 6)*13 + (qj - kj + 6);
    float x = rpb169[idx*6 + hh];
    float sig = 16.f / (1.f + __expf(-x));
    int th = type >> 1, tw = type & 1;
    int rq = (th ? (qi<4?1:2) : 0)*3 + (tw ? (qj<4?1:2) : 0);
    int rk = (th ? (ki<4?1:2) : 0)*3 + (tw ? (kj<4?1:2) : 0);
    float msk = (rq != rk) ? -100.f : 0.f;
    val = (sig + msk) * LOG2E_;
  }
  biasT[i] = val;
}

// ---------------- bf16 MFMA GEMM: out[M][NN] = act(A[M][K] @ Wt[NN][K]^T + b) -
// tile 128x192, 4 waves of 64x96; all staging/fragment addresses hoisted.
template<int K, bool GELU>
__global__ __launch_bounds__(256,2) void gemm_kernel(
    const u16* __restrict__ A, const u16* __restrict__ Wt,
    const float* __restrict__ bias, u16* __restrict__ out, int NN)
{
  __shared__ __align__(16) u16 lds[(128+192)*32];  // A: [0,4096), B: [4096,10240)
  const int tid  = threadIdx.x;
  const int wave = tid >> 6, lane = tid & 63;
  const int m0 = blockIdx.x * 128;
  const int n0 = blockIdx.y * 192;
  const int wr = wave >> 1, wc = wave & 1;   // wave tile 64 x 96
  const int lrow = lane >> 2, lslot = lane & 3;
  const int gk = (lslot ^ ((lrow >> 1) & 3)) * 8;   // pre-swizzled source slot

  // staging sources (per-thread, advance by 32 elems/iter); dests constant
  const u16* gsrc[5];
  u32 ldst[5];
#pragma unroll
  for (int t=0; t<5; t++){
    int c = wave + t*4;                     // 20 chunks: A=0..7, B=8..19
    if (c < 8) {
      gsrc[t] = A + (size_t)(m0 + c*16 + lrow)*K + gk;
      ldst[t] = c*512;
    } else {
      gsrc[t] = Wt + (size_t)(n0 + (c-8)*16 + lrow)*K + gk;
      ldst[t] = 4096 + (c-8)*512;
    }
  }
  // fragment LDS element offsets (loop-invariant)
  const int lr16 = lane & 15;
  const int slot8 = ((lane >> 4) ^ ((lr16 >> 1) & 3)) * 8;
  u32 aoff[4], boff[6];
#pragma unroll
  for (int mt=0; mt<4; mt++) aoff[mt] = (u32)((wr*64 + mt*16 + lr16)*32 + slot8);
#pragma unroll
  for (int nt=0; nt<6; nt++) boff[nt] = (u32)(4096 + (wc*96 + nt*16 + lr16)*32 + slot8);

  f32x4 acc[4][6];
#pragma unroll
  for (int mt=0; mt<4; mt++)
#pragma unroll
    for (int nt=0; nt<6; nt++)
      acc[mt][nt] = (f32x4){0.f,0.f,0.f,0.f};

#pragma unroll 6
  for (int k0 = 0; k0 < K; k0 += 32) {
#pragma unroll
    for (int t=0; t<5; t++){
      __builtin_amdgcn_global_load_lds(
          (const __attribute__((address_space(1))) void*)gsrc[t],
          (__attribute__((address_space(3))) void*)&lds[ldst[t]], 16, 0, 0);
      gsrc[t] += 32;
    }
    __syncthreads();
    bf16x8 af[4], bf[6];
#pragma unroll
    for (int mt=0; mt<4; mt++) af[mt] = *(const bf16x8*)&lds[aoff[mt]];
#pragma unroll
    for (int nt=0; nt<6; nt++) bf[nt] = *(const bf16x8*)&lds[boff[nt]];
#pragma unroll
    for (int mt=0; mt<4; mt++)
#pragma unroll
      for (int nt=0; nt<6; nt++)
        acc[mt][nt] = __builtin_amdgcn_mfma_f32_16x16x32_bf16(af[mt], bf[nt], acc[mt][nt], 0, 0, 0);
    __syncthreads();
  }
  // epilogue: C/D layout col=lane&15, row=(lane>>4)*4+reg
#pragma unroll
  for (int mt=0; mt<4; mt++){
    int rbase = m0 + wr*64 + mt*16 + (lane >> 4)*4;
#pragma unroll
    for (int nt=0; nt<6; nt++){
      int col = n0 + wc*96 + nt*16 + lr16;
      float bs = bias[col];
#pragma unroll
      for (int r2=0; r2<4; r2++){
        float v = acc[mt][nt][r2] + bs;
        if (GELU) {
          float u = v*(0.79788456f + 0.0356774081f*v*v);   // 0.797884*(1+0.044715 v^2)
          v = v / (1.f + __expf(-2.f*u));                  // == 0.5v(1+tanh(u))
        }
        out[(size_t)(rbase + r2)*NN + col] = f2bf(v);
      }
    }
  }
}

// ---------------- windowed cosine attention, MFMA ----------------------------
__global__ __launch_bounds__(64) void attn_kernel(
    const u16* __restrict__ qkv, const float* __restrict__ lsc,
    const float* __restrict__ biasT, u16* __restrict__ attn_out)
{
  __shared__ __align__(16) u16 pbuf[4096];   // P[64 q][64 key] bf16, swizzled
  const int id = blockIdx.x;
  const int hh = id % 6;
  const int w  = id / 6;
  const int b  = w >> 8;
  const int wh = (w >> 4) & 15, ww = w & 15;
  const int lane = threadIdx.x;
  const int lg = lane >> 4, lr = lane & 15;
  const int type = ((wh==15)?2:0) + ((ww==15)?1:0);
  const float qscale = __expf(fminf(lsc[hh], LOG100_)) * LOG2E_;

  union BU { bf16x8 v; u32 u[4]; };

  bf16x8 qf[4], kf[4];
#pragma unroll
  for (int mt=0; mt<4; mt++){
    int t = mt*16 + lr; if (t > 48) t = 48;
    int off = rowelem(b, wh, ww, t)*QKVN_ + hh*32 + lg*8;
    uint4 u = *(const uint4*)(qkv + off);
    float f[8]; u4_to_f8(u, f);
    float ss = 0.f;
#pragma unroll
    for (int d=0; d<8; d++) ss += f[d]*f[d];
    ss += __shfl_xor(ss, 16); ss += __shfl_xor(ss, 32);
    float rn = qscale / fmaxf(sqrtf(ss), 1e-6f);
    BU bu;
#pragma unroll
    for (int p=0; p<4; p++) bu.u[p] = pk2(f[2*p]*rn, f[2*p+1]*rn);
    qf[mt] = bu.v;
  }
#pragma unroll
  for (int nt=0; nt<4; nt++){
    int t = nt*16 + lr; if (t > 48) t = 48;
    int off = rowelem(b, wh, ww, t)*QKVN_ + 192 + hh*32 + lg*8;
    uint4 u = *(const uint4*)(qkv + off);
    float f[8]; u4_to_f8(u, f);
    float ss = 0.f;
#pragma unroll
    for (int d=0; d<8; d++) ss += f[d]*f[d];
    ss += __shfl_xor(ss, 16); ss += __shfl_xor(ss, 32);
    float rn = 1.f / fmaxf(sqrtf(ss), 1e-6f);
    BU bu;
#pragma unroll
    for (int p=0; p<4; p++) bu.u[p] = pk2(f[2*p]*rn, f[2*p+1]*rn);
    kf[nt] = bu.v;
  }

  f32x4 s[4][4];
#pragma unroll
  for (int mt=0;mt<4;mt++)
#pragma unroll
    for (int nt=0;nt<4;nt++)
      s[mt][nt] = __builtin_amdgcn_mfma_f32_16x16x32_bf16(qf[mt], kf[nt],
                    (f32x4){0.f,0.f,0.f,0.f}, 0, 0, 0);

  const float* bt = biasT + (size_t)(type*6 + hh)*4096;
#pragma unroll
  for (int nt=0;nt<4;nt++){
    int key = nt*16 + lr;
#pragma unroll
    for (int mt=0;mt<4;mt++){
      f32x4 bv = *(const f32x4*)(bt + key*64 + mt*16 + lg*4);
      s[mt][nt] += bv;
    }
  }

  float rsum[4][4];
#pragma unroll
  for (int mt=0;mt<4;mt++){
#pragma unroll
    for (int r2=0;r2<4;r2++){
      float m = fmaxf(fmaxf(s[mt][0][r2], s[mt][1][r2]),
                      fmaxf(s[mt][2][r2], s[mt][3][r2]));
      m = fmaxf(m, __shfl_xor(m, 1));
      m = fmaxf(m, __shfl_xor(m, 2));
      m = fmaxf(m, __shfl_xor(m, 4));
      m = fmaxf(m, __shfl_xor(m, 8));
      float e0 = exp2f(s[mt][0][r2]-m), e1 = exp2f(s[mt][1][r2]-m),
            e2 = exp2f(s[mt][2][r2]-m), e3 = exp2f(s[mt][3][r2]-m);
      s[mt][0][r2]=e0; s[mt][1][r2]=e1; s[mt][2][r2]=e2; s[mt][3][r2]=e3;
      float sum = (e0+e1)+(e2+e3);
      sum += __shfl_xor(sum, 1);
      sum += __shfl_xor(sum, 2);
      sum += __shfl_xor(sum, 4);
      sum += __shfl_xor(sum, 8);
      rsum[mt][r2] = 1.f/sum;
    }
  }

#pragma unroll
  for (int mt=0;mt<4;mt++)
#pragma unroll
    for (int r2=0;r2<4;r2++){
      int q = mt*16 + lg*4 + r2;
#pragma unroll
      for (int nt=0;nt<4;nt++){
        int key = nt*16 + lr;
        int addr = (q*128 + key*2) ^ ((q&7)<<4);
        *(u16*)((char*)pbuf + addr) = f2bf(s[mt][nt][r2]);
      }
    }
  __syncthreads();

  f32x4 o[4][2];
#pragma unroll
  for (int mt=0;mt<4;mt++)
#pragma unroll
    for (int dt=0;dt<2;dt++)
      o[mt][dt] = (f32x4){0.f,0.f,0.f,0.f};

#pragma unroll
  for (int kt=0; kt<2; kt++){
    bf16x8 pf[4];
#pragma unroll
    for (int mt=0;mt<4;mt++){
      int q = mt*16 + lr;
      int addr = (q*128 + kt*64 + lg*16) ^ ((q&7)<<4);
      pf[mt] = *(const bf16x8*)((char*)pbuf + addr);
    }
    int voff[8];
#pragma unroll
    for (int j=0;j<8;j++){
      int key = kt*32 + lg*8 + j; if (key > 48) key = 48;
      voff[j] = rowelem(b, wh, ww, key)*QKVN_ + 384 + hh*32 + lr;
    }
#pragma unroll
    for (int dt=0; dt<2; dt++){
      BU bu;
#pragma unroll
      for (int p=0;p<4;p++){
        u16 lo = qkv[voff[2*p]   + dt*16];
        u16 hi = qkv[voff[2*p+1] + dt*16];
        bu.u[p] = (u32)lo | ((u32)hi << 16);
      }
#pragma unroll
      for (int mt=0;mt<4;mt++)
        o[mt][dt] = __builtin_amdgcn_mfma_f32_16x16x32_bf16(pf[mt], bu.v, o[mt][dt], 0, 0, 0);
    }
  }

#pragma unroll
  for (int mt=0;mt<4;mt++)
#pragma unroll
    for (int r2=0;r2<4;r2++){
      int q = mt*16 + lg*4 + r2;
      if (q < 49){
        int off = rowelem(b, wh, ww, q)*C_ + hh*32 + lr;
        float rs = rsum[mt][r2];
        attn_out[off]      = f2bf(o[mt][0][r2]*rs);
        attn_out[off + 16] = f2bf(o[mt][1][r2]*rs);
      }
    }
}

// ------ residual + LayerNorm: out = base + LN(y)*g + b  (dtype-templated) ----
template<bool BASE32, bool OUT32>
__global__ __launch_bounds__(256) void ln_res_kernel(
    const float* __restrict__ base32, const u16* __restrict__ base16,
    const u16* __restrict__ y,
    const float* __restrict__ gg, const float* __restrict__ bb,
    float* __restrict__ out32, u16* __restrict__ out16)
{
  int row  = blockIdx.x*4 + (threadIdx.x >> 6);
  int lane = threadIdx.x & 63;
  size_t ro = (size_t)row*192;
  float v0 = bf2f(y[ro+lane]), v1 = bf2f(y[ro+lane+64]), v2 = bf2f(y[ro+lane+128]);
  float s  = v0+v1+v2;
  float sq = v0*v0+v1*v1+v2*v2;
#pragma unroll
  for (int m=32; m>=1; m>>=1){ s += __shfl_xor(s,m); sq += __shfl_xor(sq,m); }
  float mean = s*(1.f/192.f);
  float var  = fmaxf(sq*(1.f/192.f) - mean*mean, 0.f);
  float rstd = rsqrtf(var + 1e-5f);
  float g0=gg[lane], g1=gg[lane+64], g2=gg[lane+128];
  float b0=bb[lane], b1=bb[lane+64], b2=bb[lane+128];
  float a0, a1, a2;
  if (BASE32) { a0=base32[ro+lane]; a1=base32[ro+lane+64]; a2=base32[ro+lane+128]; }
  else        { a0=bf2f(base16[ro+lane]); a1=bf2f(base16[ro+lane+64]); a2=bf2f(base16[ro+lane+128]); }
  float r0 = a0 + (v0-mean)*rstd*g0 + b0;
  float r1 = a1 + (v1-mean)*rstd*g1 + b1;
  float r2 = a2 + (v2-mean)*rstd*g2 + b2;
  if (OUT32) {
    out32[ro+lane] = r0; out32[ro+lane+64] = r1; out32[ro+lane+128] = r2;
  } else {
    out16[ro+lane] = f2bf(r0); out16[ro+lane+64] = f2bf(r1); out16[ro+lane+128] = f2bf(r2);
  }
}

// ---------------- launch ------------------------------------------------------
extern "C" void kernel_launch(void* const* d_in, const int* in_sizes, int n_in,
                              void* d_out, int out_size, void* d_ws, size_t ws_size,
                              hipStream_t stream)
{
  (void)in_sizes; (void)n_in; (void)out_size; (void)ws_size;
  const float* x      = (const float*)d_in[0];
  const float* q_w    = (const float*)d_in[1];
  const float* q_b    = (const float*)d_in[2];
  const float* k_w    = (const float*)d_in[3];
  const float* v_w    = (const float*)d_in[4];
  const float* v_b    = (const float*)d_in[5];
  const float* proj_w = (const float*)d_in[6];
  const float* proj_b = (const float*)d_in[7];
  const float* lsc    = (const float*)d_in[8];
  const float* cpb_w0 = (const float*)d_in[9];
  const float* cpb_b0 = (const float*)d_in[10];
  const float* cpb_w1 = (const float*)d_in[11];
  const float* ln1_g  = (const float*)d_in[12];
  const float* ln1_b  = (const float*)d_in[13];
  const float* ln2_g  = (const float*)d_in[14];
  const float* ln2_b  = (const float*)d_in[15];
  const float* fc1_w  = (const float*)d_in[16];
  const float* fc1_b  = (const float*)d_in[17];
  const float* fc2_w  = (const float*)d_in[18];
  const float* fc2_b  = (const float*)d_in[19];

  char* ws = (char*)d_ws;
  size_t o = 0;
  u16* qkvb = (u16*)(ws + o);
  u16* mid  = qkvb;              o += 154140672;
  u16* x_bf   = (u16*)(ws + o);
  u16* attn_o = x_bf;
  u16* h1b    = x_bf;            o += 38535168;
  u16* proj_o = (u16*)(ws + o);
  u16* m2     = proj_o;          o += 38535168;
  u16* wt_qkv = (u16*)(ws + o);  o += 221184;
  float* b_qkv= (float*)(ws + o);o += 2304;
  u16* wt_p   = (u16*)(ws + o);  o += 73728;
  float* b_p  = (float*)(ws + o);o += 768;
  u16* wt_f1  = (u16*)(ws + o);  o += 294912;
  float* b_f1 = (float*)(ws + o);o += 3072;
  u16* wt_f2  = (u16*)(ws + o);  o += 294912;
  float* b_f2 = (float*)(ws + o);o += 768;
  float* rpb169 = (float*)(ws + o); o += 4096;
  float* biasT  = (float*)(ws + o); o += 393216;

  prep_weights<<<1735, 256, 0, stream>>>(q_w, q_b, k_w, v_w, v_b, proj_w, proj_b,
      fc1_w, fc1_b, fc2_w, fc2_b, wt_qkv, b_qkv, wt_p, b_p, wt_f1, b_f1, wt_f2, b_f2);
  rpb_a_kernel<<<169, 64, 0, stream>>>(cpb_w0, cpb_b0, cpb_w1, rpb169);
  rpb_b_kernel<<<384, 256, 0, stream>>>(rpb169, biasT);
  f2bf_kernel<<<9408, 256, 0, stream>>>(x, x_bf, M_*C_);

  gemm_kernel<192,false><<<dim3(784,3), 256, 0, stream>>>(x_bf, wt_qkv, b_qkv, qkvb, 576);
  attn_kernel<<<12288, 64, 0, stream>>>(qkvb, lsc, biasT, attn_o);
  gemm_kernel<192,false><<<dim3(784,1), 256, 0, stream>>>(attn_o, wt_p, b_p, proj_o, 192);
  ln_res_kernel<true,false><<<25088, 256, 0, stream>>>(x, nullptr, proj_o,
      ln1_g, ln1_b, nullptr, h1b);
  gemm_kernel<192,true><<<dim3(784,4), 256, 0, stream>>>(h1b, wt_f1, b_f1, mid, 768);
  gemm_kernel<768,false><<<dim3(784,1), 256, 0, stream>>>(mid, wt_f2, b_f2, m2, 192);
  ln_res_kernel<false,true><<<25088, 256, 0, stream>>>(nullptr, h1b, m2,
      ln2_g, ln2_b, (float*)d_out, nullptr);
}

// Round 5
// 359.680 us; speedup vs baseline: 1.4208x; 1.0646x over previous
//
#include <hip/hip_runtime.h>

typedef unsigned short u16;
typedef unsigned int   u32;
typedef __attribute__((ext_vector_type(8))) short bf16x8;
typedef __attribute__((ext_vector_type(4))) float f32x4;

#define B_      8
#define HW_     112
#define C_      192
#define NH_     6
#define HD_     32
#define L_      (HW_*HW_)       // 12544
#define M_      (B_*L_)         // 100352
#define MLP_    768
#define QKVN_   576
#define LOG100_ 4.6051702f
#define LOG2E_  1.44269504f

__device__ __forceinline__ float bf2f(u16 u){
  union { float f; u32 i; } v; v.i = ((u32)u) << 16; return v.f;
}
__device__ __forceinline__ u16 f2bf(float f){
  union { float f; u32 i; } v; v.f = f;
  u32 r = (v.i + 0x7fffu + ((v.i >> 16) & 1u)) >> 16;
  return (u16)r;
}
__device__ __forceinline__ u32 pk2(float a, float b){
  return (u32)f2bf(a) | ((u32)f2bf(b) << 16);
}
__device__ __forceinline__ void u4_to_f8(uint4 u, float* f){
  f[0]=bf2f((u16)(u.x&0xffffu)); f[1]=bf2f((u16)(u.x>>16));
  f[2]=bf2f((u16)(u.y&0xffffu)); f[3]=bf2f((u16)(u.y>>16));
  f[4]=bf2f((u16)(u.z&0xffffu)); f[5]=bf2f((u16)(u.z>>16));
  f[6]=bf2f((u16)(u.w&0xffffu)); f[7]=bf2f((u16)(u.w>>16));
}

// local window index t (0..48) -> token row (elements) with reverse cyclic shift
__device__ __forceinline__ int rowelem(int b, int wh, int ww, int t){
  int i = t/7, j = t - i*7;
  int oi = wh*7 + i + 3; if (oi >= 112) oi -= 112;
  int oj = ww*7 + j + 3; if (oj >= 112) oj -= 112;
  return b*L_ + oi*112 + oj;
}

// ---------------- weight prep: transpose to [N][K] bf16, biases f32 ----------
__global__ __launch_bounds__(256) void prep_weights(
    const float* __restrict__ qw, const float* __restrict__ qb,
    const float* __restrict__ kw, const float* __restrict__ vw,
    const float* __restrict__ vb, const float* __restrict__ pw,
    const float* __restrict__ pb, const float* __restrict__ f1w,
    const float* __restrict__ f1b, const float* __restrict__ f2w,
    const float* __restrict__ f2b,
    u16* __restrict__ wt_qkv, float* __restrict__ b_qkv,
    u16* __restrict__ wt_p,   float* __restrict__ b_p,
    u16* __restrict__ wt_f1,  float* __restrict__ b_f1,
    u16* __restrict__ wt_f2,  float* __restrict__ b_f2)
{
  const int S1 = 110592, S2 = 147456, S3 = 294912, S4 = 442368, TOT = 444096;
  int i = blockIdx.x*256 + threadIdx.x;
  if (i >= TOT) return;
  if (i < S1) {                       // wt_qkv[576][192]
    int n = i/192, k = i%192;
    float v = (n<192) ? qw[k*192+n] : ((n<384) ? kw[k*192+(n-192)] : vw[k*192+(n-384)]);
    wt_qkv[i] = f2bf(v);
  } else if (i < S2) {                // wt_p[192][192]
    int j = i - S1; int n = j/192, k = j%192;
    wt_p[j] = f2bf(pw[k*192+n]);
  } else if (i < S3) {                // wt_f1[768][192]
    int j = i - S2; int n = j/192, k = j%192;
    wt_f1[j] = f2bf(f1w[k*768+n]);
  } else if (i < S4) {                // wt_f2[192][768]
    int j = i - S3; int n = j/768, k = j%768;
    wt_f2[j] = f2bf(f2w[k*192+n]);
  } else {
    int j = i - S4;
    if (j < 576)        b_qkv[j] = (j<192) ? qb[j] : ((j<384) ? 0.f : vb[j-384]);
    else if (j < 768)   b_p[j-576]   = pb[j-576];
    else if (j < 1536)  b_f1[j-768]  = f1b[j-768];
    else                b_f2[j-1536] = f2b[j-1536];
  }
}

// ---------------- relative position bias ------------------------------------
__device__ __forceinline__ float reltab(float x){
  float v = x * (8.f/6.f);
  float r = __log2f(fabsf(v) + 1.f) * (1.f/3.f);
  return (v < 0.f) ? -r : r;
}

__global__ __launch_bounds__(64) void rpb_a_kernel(
    const float* __restrict__ w0, const float* __restrict__ b0,
    const float* __restrict__ w1, float* __restrict__ rpb169)
{
  int tt = blockIdx.x, lane = threadIdx.x;
  float t0 = reltab((float)(tt/13 - 6));
  float t1 = reltab((float)(tt%13 - 6));
  float acc[6] = {0.f,0.f,0.f,0.f,0.f,0.f};
  for (int j = lane; j < 512; j += 64){
    float hid = fmaxf(t0*w0[j] + t1*w0[512+j] + b0[j], 0.f);
#pragma unroll
    for (int h=0; h<6; h++) acc[h] += hid * w1[j*6+h];
  }
#pragma unroll
  for (int h=0; h<6; h++){
#pragma unroll
    for (int m=32; m>=1; m>>=1) acc[h] += __shfl_xor(acc[h], m);
  }
  if (lane == 0){
#pragma unroll
    for (int h=0; h<6; h++) rpb169[tt*6+h] = acc[h];
  }
}

// biasT[type][head][key(64)][q(64)] = (16*sigmoid(rpb) + mask) * log2(e)
__global__ __launch_bounds__(256) void rpb_b_kernel(
    const float* __restrict__ rpb169, float* __restrict__ biasT)
{
  int i = blockIdx.x*256 + threadIdx.x;   // 4*6*64*64 = 98304
  if (i >= 98304) return;
  int q = i & 63, key = (i >> 6) & 63;
  int rest = i >> 12;                      // 0..23
  int hh = rest % 6, type = rest / 6;
  float val;
  if (key >= 49) val = -60000.f;
  else if (q >= 49) val = 0.f;
  else {
    int qi = q/7, qj = q%7, ki = key/7, kj = key%7;
    int idx = (qi - ki + 6)*13 + (qj - kj + 6);
    float x = rpb169[idx*6 + hh];
    float sig = 16.f / (1.f + __expf(-x));
    int th = type >> 1, tw = type & 1;
    int rq = (th ? (qi<4?1:2) : 0)*3 + (tw ? (qj<4?1:2) : 0);
    int rk = (th ? (ki<4?1:2) : 0)*3 + (tw ? (kj<4?1:2) : 0);
    float msk = (rq != rk) ? -100.f : 0.f;
    val = (sig + msk) * LOG2E_;
  }
  biasT[i] = val;
}

// ======================= GEMM common pieces ==================================
// tile 128x192, BK=32, 512 threads = 8 waves of 32x96.
// LDS elems: A [0,4096), B [4096,10240). XOR slot swizzle: slot^((row>>1)&3).

__device__ __forceinline__ float fast_gelu(float v){
  // 0.5*v*(1+tanh(0.79788456*(v+0.044715 v^3))) == v*sigmoid(2u)
  float t = v*v;
  float w = v * fmaf(-0.1029432f, t, -2.30220817f);   // -2u*log2(e)
  float e = exp2f(w);
  return v * __builtin_amdgcn_rcpf(1.f + e);
}

// ---- generic bf16-A GEMM: out = act(A[M][K] @ Wt[NN][K]^T + bias) -----------
template<int K, bool GELU>
__global__ __launch_bounds__(512,4) void gemm_kernel(
    const u16* __restrict__ A, const u16* __restrict__ Wt,
    const float* __restrict__ bias, u16* __restrict__ out, int NN)
{
  __shared__ __align__(16) u16 lds[10240];
  const int tid  = threadIdx.x;
  const int wave = tid >> 6, lane = tid & 63;
  const int m0 = blockIdx.x * 128;
  const int n0 = blockIdx.y * 192;
  const int wr = wave >> 1, wc = wave & 1;     // wave tile 32 x 96
  const int lrow = lane >> 2, lslot = lane & 3;
  const int gk = (lslot ^ ((lrow >> 1) & 3)) * 8;

  // staging: 20 chunks of 1KiB (A:0..7, B:8..19); wave w -> {w, w+8, w+16?}
  const u16* gsrc[3]; u32 ldst[3]; int nst = (wave < 4) ? 3 : 2;
#pragma unroll
  for (int t=0; t<3; t++){
    int c = wave + t*8;
    if (c < 8)       { gsrc[t] = A  + (size_t)(m0 + c*16 + lrow)*K + gk;      ldst[t] = c*512; }
    else if (c < 20) { gsrc[t] = Wt + (size_t)(n0 + (c-8)*16 + lrow)*K + gk;  ldst[t] = 4096 + (c-8)*512; }
  }
  const int lr16 = lane & 15;
  const int slot8 = ((lane >> 4) ^ ((lr16 >> 1) & 3)) * 8;
  u32 aoff[2], boff[6];
#pragma unroll
  for (int mt=0; mt<2; mt++) aoff[mt] = (u32)((wr*32 + mt*16 + lr16)*32 + slot8);
#pragma unroll
  for (int nt=0; nt<6; nt++) boff[nt] = (u32)(4096 + (wc*96 + nt*16 + lr16)*32 + slot8);

  float bs[6];
#pragma unroll
  for (int nt=0; nt<6; nt++) bs[nt] = bias[n0 + wc*96 + nt*16 + lr16];

  f32x4 acc[2][6];
#pragma unroll
  for (int mt=0; mt<2; mt++)
#pragma unroll
    for (int nt=0; nt<6; nt++)
      acc[mt][nt] = (f32x4){0.f,0.f,0.f,0.f};

  for (int k0 = 0; k0 < K; k0 += 32) {
#pragma unroll
    for (int t=0; t<3; t++){
      if (t < nst) {
        __builtin_amdgcn_global_load_lds(
            (const __attribute__((address_space(1))) void*)gsrc[t],
            (__attribute__((address_space(3))) void*)&lds[ldst[t]], 16, 0, 0);
        gsrc[t] += 32;
      }
    }
    __syncthreads();
    bf16x8 af[2], bf[6];
#pragma unroll
    for (int mt=0; mt<2; mt++) af[mt] = *(const bf16x8*)&lds[aoff[mt]];
#pragma unroll
    for (int nt=0; nt<6; nt++) bf[nt] = *(const bf16x8*)&lds[boff[nt]];
#pragma unroll
    for (int mt=0; mt<2; mt++)
#pragma unroll
      for (int nt=0; nt<6; nt++)
        acc[mt][nt] = __builtin_amdgcn_mfma_f32_16x16x32_bf16(af[mt], bf[nt], acc[mt][nt], 0, 0, 0);
    __syncthreads();
  }
#pragma unroll
  for (int mt=0; mt<2; mt++){
    int rbase = m0 + wr*32 + mt*16 + (lane >> 4)*4;
#pragma unroll
    for (int nt=0; nt<6; nt++){
      int col = n0 + wc*96 + nt*16 + lr16;
#pragma unroll
      for (int r2=0; r2<4; r2++){
        float v = acc[mt][nt][r2] + bs[nt];
        if (GELU) v = fast_gelu(v);
        out[(size_t)(rbase + r2)*NN + col] = f2bf(v);
      }
    }
  }
}

// ---- QKV GEMM: A is f32 x (reg-staged + converted), NN=576 ------------------
__global__ __launch_bounds__(512,4) void gemm_qkv_kernel(
    const float* __restrict__ X, const u16* __restrict__ Wt,
    const float* __restrict__ bias, u16* __restrict__ out)
{
  __shared__ __align__(16) u16 lds[10240];
  const int tid  = threadIdx.x;
  const int wave = tid >> 6, lane = tid & 63;
  const int m0 = blockIdx.x * 128;
  const int n0 = blockIdx.y * 192;
  const int wr = wave >> 1, wc = wave & 1;
  const int lrow = lane >> 2, lslot = lane & 3;
  const int gk = (lslot ^ ((lrow >> 1) & 3)) * 8;

  // B staging: 12 chunks; wave w -> {w}, w<4 -> {8+w}
  const u16* gsrcB[2]; u32 ldstB[2]; int nstB = (wave < 4) ? 2 : 1;
#pragma unroll
  for (int t=0; t<2; t++){
    int c = wave + t*8;
    if (c < 12) { gsrcB[t] = Wt + (size_t)(n0 + c*16 + lrow)*192 + gk; ldstB[t] = 4096 + c*512; }
  }
  // A staging: thread -> row r=tid>>2 (0..127), slot s=tid&3; f32 source
  const int ar = tid >> 2, as = tid & 3;
  const float* gsrcA = X + (size_t)(m0 + ar)*192 + as*8;
  const u32 dsta = (u32)(ar*32 + (as ^ ((ar >> 1) & 3))*8);

  const int lr16 = lane & 15;
  const int slot8 = ((lane >> 4) ^ ((lr16 >> 1) & 3)) * 8;
  u32 aoff[2], boff[6];
#pragma unroll
  for (int mt=0; mt<2; mt++) aoff[mt] = (u32)((wr*32 + mt*16 + lr16)*32 + slot8);
#pragma unroll
  for (int nt=0; nt<6; nt++) boff[nt] = (u32)(4096 + (wc*96 + nt*16 + lr16)*32 + slot8);

  float bs[6];
#pragma unroll
  for (int nt=0; nt<6; nt++) bs[nt] = bias[n0 + wc*96 + nt*16 + lr16];

  f32x4 acc[2][6];
#pragma unroll
  for (int mt=0; mt<2; mt++)
#pragma unroll
    for (int nt=0; nt<6; nt++)
      acc[mt][nt] = (f32x4){0.f,0.f,0.f,0.f};

  for (int k0 = 0; k0 < 192; k0 += 32) {
#pragma unroll
    for (int t=0; t<2; t++){
      if (t < nstB) {
        __builtin_amdgcn_global_load_lds(
            (const __attribute__((address_space(1))) void*)gsrcB[t],
            (__attribute__((address_space(3))) void*)&lds[ldstB[t]], 16, 0, 0);
        gsrcB[t] += 32;
      }
    }
    float4 a0 = *(const float4*)gsrcA;
    float4 a1 = *(const float4*)(gsrcA + 4);
    gsrcA += 32;
    uint4 aw;
    aw.x = pk2(a0.x, a0.y); aw.y = pk2(a0.z, a0.w);
    aw.z = pk2(a1.x, a1.y); aw.w = pk2(a1.z, a1.w);
    *(uint4*)(void*)&lds[dsta] = aw;
    __syncthreads();
    bf16x8 af[2], bf[6];
#pragma unroll
    for (int mt=0; mt<2; mt++) af[mt] = *(const bf16x8*)&lds[aoff[mt]];
#pragma unroll
    for (int nt=0; nt<6; nt++) bf[nt] = *(const bf16x8*)&lds[boff[nt]];
#pragma unroll
    for (int mt=0; mt<2; mt++)
#pragma unroll
      for (int nt=0; nt<6; nt++)
        acc[mt][nt] = __builtin_amdgcn_mfma_f32_16x16x32_bf16(af[mt], bf[nt], acc[mt][nt], 0, 0, 0);
    __syncthreads();
  }
#pragma unroll
  for (int mt=0; mt<2; mt++){
    int rbase = m0 + wr*32 + mt*16 + (lane >> 4)*4;
#pragma unroll
    for (int nt=0; nt<6; nt++){
      int col = n0 + wc*96 + nt*16 + lr16;
#pragma unroll
      for (int r2=0; r2<4; r2++){
        float v = acc[mt][nt][r2] + bs[nt];
        out[(size_t)(rbase + r2)*QKVN_ + col] = f2bf(v);
      }
    }
  }
}

// ---------------- windowed cosine attention, MFMA ----------------------------
__global__ __launch_bounds__(64) void attn_kernel(
    const u16* __restrict__ qkv, const float* __restrict__ lsc,
    const float* __restrict__ biasT, u16* __restrict__ attn_out)
{
  __shared__ __align__(16) u16 pbuf[4096];   // P[64 q][64 key] bf16, swizzled
  const int id = blockIdx.x;
  const int hh = id % 6;
  const int w  = id / 6;
  const int b  = w >> 8;
  const int wh = (w >> 4) & 15, ww = w & 15;
  const int lane = threadIdx.x;
  const int lg = lane >> 4, lr = lane & 15;
  const int type = ((wh==15)?2:0) + ((ww==15)?1:0);
  const float qscale = __expf(fminf(lsc[hh], LOG100_)) * LOG2E_;

  union BU { bf16x8 v; u32 u[4]; };

  bf16x8 qf[4], kf[4];
#pragma unroll
  for (int mt=0; mt<4; mt++){
    int t = mt*16 + lr; if (t > 48) t = 48;
    int off = rowelem(b, wh, ww, t)*QKVN_ + hh*32 + lg*8;
    uint4 u = *(const uint4*)(qkv + off);
    float f[8]; u4_to_f8(u, f);
    float ss = 0.f;
#pragma unroll
    for (int d=0; d<8; d++) ss += f[d]*f[d];
    ss += __shfl_xor(ss, 16); ss += __shfl_xor(ss, 32);
    float rn = qscale / fmaxf(sqrtf(ss), 1e-6f);
    BU bu;
#pragma unroll
    for (int p=0; p<4; p++) bu.u[p] = pk2(f[2*p]*rn, f[2*p+1]*rn);
    qf[mt] = bu.v;
  }
#pragma unroll
  for (int nt=0; nt<4; nt++){
    int t = nt*16 + lr; if (t > 48) t = 48;
    int off = rowelem(b, wh, ww, t)*QKVN_ + 192 + hh*32 + lg*8;
    uint4 u = *(const uint4*)(qkv + off);
    float f[8]; u4_to_f8(u, f);
    float ss = 0.f;
#pragma unroll
    for (int d=0; d<8; d++) ss += f[d]*f[d];
    ss += __shfl_xor(ss, 16); ss += __shfl_xor(ss, 32);
    float rn = 1.f / fmaxf(sqrtf(ss), 1e-6f);
    BU bu;
#pragma unroll
    for (int p=0; p<4; p++) bu.u[p] = pk2(f[2*p]*rn, f[2*p+1]*rn);
    kf[nt] = bu.v;
  }

  f32x4 s[4][4];
#pragma unroll
  for (int mt=0;mt<4;mt++)
#pragma unroll
    for (int nt=0;nt<4;nt++)
      s[mt][nt] = __builtin_amdgcn_mfma_f32_16x16x32_bf16(qf[mt], kf[nt],
                    (f32x4){0.f,0.f,0.f,0.f}, 0, 0, 0);

  const float* bt = biasT + (size_t)(type*6 + hh)*4096;
#pragma unroll
  for (int nt=0;nt<4;nt++){
    int key = nt*16 + lr;
#pragma unroll
    for (int mt=0;mt<4;mt++){
      f32x4 bv = *(const f32x4*)(bt + key*64 + mt*16 + lg*4);
      s[mt][nt] += bv;
    }
  }

  float rsum[4][4];
#pragma unroll
  for (int mt=0;mt<4;mt++){
#pragma unroll
    for (int r2=0;r2<4;r2++){
      float m = fmaxf(fmaxf(s[mt][0][r2], s[mt][1][r2]),
                      fmaxf(s[mt][2][r2], s[mt][3][r2]));
      m = fmaxf(m, __shfl_xor(m, 1));
      m = fmaxf(m, __shfl_xor(m, 2));
      m = fmaxf(m, __shfl_xor(m, 4));
      m = fmaxf(m, __shfl_xor(m, 8));
      float e0 = exp2f(s[mt][0][r2]-m), e1 = exp2f(s[mt][1][r2]-m),
            e2 = exp2f(s[mt][2][r2]-m), e3 = exp2f(s[mt][3][r2]-m);
      s[mt][0][r2]=e0; s[mt][1][r2]=e1; s[mt][2][r2]=e2; s[mt][3][r2]=e3;
      float sum = (e0+e1)+(e2+e3);
      sum += __shfl_xor(sum, 1);
      sum += __shfl_xor(sum, 2);
      sum += __shfl_xor(sum, 4);
      sum += __shfl_xor(sum, 8);
      rsum[mt][r2] = 1.f/sum;
    }
  }

#pragma unroll
  for (int mt=0;mt<4;mt++)
#pragma unroll
    for (int r2=0;r2<4;r2++){
      int q = mt*16 + lg*4 + r2;
#pragma unroll
      for (int nt=0;nt<4;nt++){
        int key = nt*16 + lr;
        int addr = (q*128 + key*2) ^ ((q&7)<<4);
        *(u16*)((char*)pbuf + addr) = f2bf(s[mt][nt][r2]);
      }
    }
  __syncthreads();

  f32x4 o[4][2];
#pragma unroll
  for (int mt=0;mt<4;mt++)
#pragma unroll
    for (int dt=0;dt<2;dt++)
      o[mt][dt] = (f32x4){0.f,0.f,0.f,0.f};

#pragma unroll
  for (int kt=0; kt<2; kt++){
    bf16x8 pf[4];
#pragma unroll
    for (int mt=0;mt<4;mt++){
      int q = mt*16 + lr;
      int addr = (q*128 + kt*64 + lg*16) ^ ((q&7)<<4);
      pf[mt] = *(const bf16x8*)((char*)pbuf + addr);
    }
    int voff[8];
#pragma unroll
    for (int j=0;j<8;j++){
      int key = kt*32 + lg*8 + j; if (key > 48) key = 48;
      voff[j] = rowelem(b, wh, ww, key)*QKVN_ + 384 + hh*32 + lr;
    }
#pragma unroll
    for (int dt=0; dt<2; dt++){
      BU bu;
#pragma unroll
      for (int p=0;p<4;p++){
        u16 lo = qkv[voff[2*p]   + dt*16];
        u16 hi = qkv[voff[2*p+1] + dt*16];
        bu.u[p] = (u32)lo | ((u32)hi << 16);
      }
#pragma unroll
      for (int mt=0;mt<4;mt++)
        o[mt][dt] = __builtin_amdgcn_mfma_f32_16x16x32_bf16(pf[mt], bu.v, o[mt][dt], 0, 0, 0);
    }
  }

#pragma unroll
  for (int mt=0;mt<4;mt++)
#pragma unroll
    for (int r2=0;r2<4;r2++){
      int q = mt*16 + lg*4 + r2;
      if (q < 49){
        int off = rowelem(b, wh, ww, q)*C_ + hh*32 + lr;
        float rs = rsum[mt][r2];
        attn_out[off]      = f2bf(o[mt][0][r2]*rs);
        attn_out[off + 16] = f2bf(o[mt][1][r2]*rs);
      }
    }
}

// ------ residual + LayerNorm: out = base + LN(y)*g + b  (dtype-templated) ----
template<bool BASE32, bool OUT32>
__global__ __launch_bounds__(256) void ln_res_kernel(
    const float* __restrict__ base32, const u16* __restrict__ base16,
    const u16* __restrict__ y,
    const float* __restrict__ gg, const float* __restrict__ bb,
    float* __restrict__ out32, u16* __restrict__ out16)
{
  int row  = blockIdx.x*4 + (threadIdx.x >> 6);
  int lane = threadIdx.x & 63;
  size_t ro = (size_t)row*192;
  float v0 = bf2f(y[ro+lane]), v1 = bf2f(y[ro+lane+64]), v2 = bf2f(y[ro+lane+128]);
  float s  = v0+v1+v2;
  float sq = v0*v0+v1*v1+v2*v2;
#pragma unroll
  for (int m=32; m>=1; m>>=1){ s += __shfl_xor(s,m); sq += __shfl_xor(sq,m); }
  float mean = s*(1.f/192.f);
  float var  = fmaxf(sq*(1.f/192.f) - mean*mean, 0.f);
  float rstd = rsqrtf(var + 1e-5f);
  float g0=gg[lane], g1=gg[lane+64], g2=gg[lane+128];
  float b0=bb[lane], b1=bb[lane+64], b2=bb[lane+128];
  float a0, a1, a2;
  if (BASE32) { a0=base32[ro+lane]; a1=base32[ro+lane+64]; a2=base32[ro+lane+128]; }
  else        { a0=bf2f(base16[ro+lane]); a1=bf2f(base16[ro+lane+64]); a2=bf2f(base16[ro+lane+128]); }
  float r0 = a0 + (v0-mean)*rstd*g0 + b0;
  float r1 = a1 + (v1-mean)*rstd*g1 + b1;
  float r2 = a2 + (v2-mean)*rstd*g2 + b2;
  if (OUT32) {
    out32[ro+lane] = r0; out32[ro+lane+64] = r1; out32[ro+lane+128] = r2;
  } else {
    out16[ro+lane] = f2bf(r0); out16[ro+lane+64] = f2bf(r1); out16[ro+lane+128] = f2bf(r2);
  }
}

// ---------------- launch ------------------------------------------------------
extern "C" void kernel_launch(void* const* d_in, const int* in_sizes, int n_in,
                              void* d_out, int out_size, void* d_ws, size_t ws_size,
                              hipStream_t stream)
{
  (void)in_sizes; (void)n_in; (void)out_size; (void)ws_size;
  const float* x      = (const float*)d_in[0];
  const float* q_w    = (const float*)d_in[1];
  const float* q_b    = (const float*)d_in[2];
  const float* k_w    = (const float*)d_in[3];
  const float* v_w    = (const float*)d_in[4];
  const float* v_b    = (const float*)d_in[5];
  const float* proj_w = (const float*)d_in[6];
  const float* proj_b = (const float*)d_in[7];
  const float* lsc    = (const float*)d_in[8];
  const float* cpb_w0 = (const float*)d_in[9];
  const float* cpb_b0 = (const float*)d_in[10];
  const float* cpb_w1 = (const float*)d_in[11];
  const float* ln1_g  = (const float*)d_in[12];
  const float* ln1_b  = (const float*)d_in[13];
  const float* ln2_g  = (const float*)d_in[14];
  const float* ln2_b  = (const float*)d_in[15];
  const float* fc1_w  = (const float*)d_in[16];
  const float* fc1_b  = (const float*)d_in[17];
  const float* fc2_w  = (const float*)d_in[18];
  const float* fc2_b  = (const float*)d_in[19];

  char* ws = (char*)d_ws;
  size_t o = 0;
  u16* qkvb = (u16*)(ws + o);
  u16* mid  = qkvb;              o += 154140672;
  u16* attn_o = (u16*)(ws + o);
  u16* h1b    = attn_o;          o += 38535168;
  u16* proj_o = (u16*)(ws + o);
  u16* m2     = proj_o;          o += 38535168;
  u16* wt_qkv = (u16*)(ws + o);  o += 221184;
  float* b_qkv= (float*)(ws + o);o += 2304;
  u16* wt_p   = (u16*)(ws + o);  o += 73728;
  float* b_p  = (float*)(ws + o);o += 768;
  u16* wt_f1  = (u16*)(ws + o);  o += 294912;
  float* b_f1 = (float*)(ws + o);o += 3072;
  u16* wt_f2  = (u16*)(ws + o);  o += 294912;
  float* b_f2 = (float*)(ws + o);o += 768;
  float* rpb169 = (float*)(ws + o); o += 4096;
  float* biasT  = (float*)(ws + o); o += 393216;

  prep_weights<<<1735, 256, 0, stream>>>(q_w, q_b, k_w, v_w, v_b, proj_w, proj_b,
      fc1_w, fc1_b, fc2_w, fc2_b, wt_qkv, b_qkv, wt_p, b_p, wt_f1, b_f1, wt_f2, b_f2);
  rpb_a_kernel<<<169, 64, 0, stream>>>(cpb_w0, cpb_b0, cpb_w1, rpb169);
  rpb_b_kernel<<<384, 256, 0, stream>>>(rpb169, biasT);

  gemm_qkv_kernel<<<dim3(784,3), 512, 0, stream>>>(x, wt_qkv, b_qkv, qkvb);
  attn_kernel<<<12288, 64, 0, stream>>>(qkvb, lsc, biasT, attn_o);
  gemm_kernel<192,false><<<dim3(784,1), 512, 0, stream>>>(attn_o, wt_p, b_p, proj_o, 192);
  ln_res_kernel<true,false><<<25088, 256, 0, stream>>>(x, nullptr, proj_o,
      ln1_g, ln1_b, nullptr, h1b);
  gemm_kernel<192,true><<<dim3(784,4), 512, 0, stream>>>(h1b, wt_f1, b_f1, mid, 768);
  gemm_kernel<768,false><<<dim3(784,1), 512, 0, stream>>>(mid, wt_f2, b_f2, m2, 192);
  ln_res_kernel<false,true><<<25088, 256, 0, stream>>>(nullptr, h1b, m2,
      ln2_g, ln2_b, (float*)d_out, nullptr);
}